// Round 22
// baseline (1198.663 us; speedup 1.0000x reference)
//
#include <hip/hip_runtime.h>
#include <stdint.h>

#define T_SEQ 128
#define B_SZ  32
#define H_DIM 1024
#define E_DIM 512
#define V_DIM 32000
#define SOS_TOK 1
#define NCONS 128     // consumers; fewer -> less fabric pressure on producers
#define NTILES 8000   // 32 mtp x 250 nt (BBF=false path)
#define NPAIR 4000    // 16 m2 x 250 nt  (BBF=true paired path)

typedef float v4f __attribute__((ext_vector_type(4)));
typedef short short8 __attribute__((ext_vector_type(8)));

// RNE float->bf16
__device__ inline uint16_t f2bf(float x) {
    uint32_t u = __float_as_uint(x);
    uint32_t r = (u + 0x7fffu + ((u >> 16) & 1u)) >> 16;
    return (uint16_t)r;
}
__device__ inline uint32_t pack2(float a, float b) {
    return (uint32_t)f2bf(a) | ((uint32_t)f2bf(b) << 16);
}

// async global->LDS, 16B per lane. lds base must be wave-uniform.
__device__ inline void gload16(const void* g, void* l) {
    __builtin_amdgcn_global_load_lds(
        (const __attribute__((address_space(1))) uint32_t*)g,
        (__attribute__((address_space(3))) uint32_t*)l, 16, 0, 0);
}

// ---------------------------------------------------------------------------
// kprep: single prologue launch (verbatim R21).
//   blocks [0,512)        : Whh fp32->bf16
//   blocks [512,528)      : h0 fp32->bf16
//   block  528            : zero flags
//   blocks [529,785)      : kxwm GEMM (xW = emb[tok].Wih^T + biases)
//   blocks [785,785+16000): Wout fp32->bf16 (only when wbok)
// ---------------------------------------------------------------------------
__global__ __launch_bounds__(256) void kprep(const float* __restrict__ Whh,
                                             uint16_t* __restrict__ WbHH,
                                             const float* __restrict__ h0,
                                             uint16_t* __restrict__ hbInit,
                                             uint32_t* __restrict__ flags,
                                             const int* __restrict__ target,
                                             const float* __restrict__ emb,
                                             const float* __restrict__ Wih,
                                             const float* __restrict__ bih,
                                             const float* __restrict__ bhh,
                                             float* __restrict__ xW,
                                             const float* __restrict__ Wout,
                                             uint16_t* __restrict__ WbOut) {
    __shared__ __align__(16) uint16_t As[128 * 32];
    __shared__ __align__(16) uint16_t Bs[128 * 32];
    __shared__ int toks[128];
    int bid = blockIdx.x;
    int tid = threadIdx.x;

    if (bid < 512) {                      // Whh conversion
        size_t i = ((size_t)bid * 256 + tid) * 8;
        float4 a = *(const float4*)&Whh[i];
        float4 c = *(const float4*)&Whh[i + 4];
        uint4 p;
        p.x = pack2(a.x, a.y); p.y = pack2(a.z, a.w);
        p.z = pack2(c.x, c.y); p.w = pack2(c.z, c.w);
        *(uint4*)&WbHH[i] = p;
        return;
    }
    if (bid < 528) {                      // h0 conversion
        size_t i = ((size_t)(bid - 512) * 256 + tid) * 8;
        float4 a = *(const float4*)&h0[i];
        float4 c = *(const float4*)&h0[i + 4];
        uint4 p;
        p.x = pack2(a.x, a.y); p.y = pack2(a.z, a.w);
        p.z = pack2(c.x, c.y); p.w = pack2(c.z, c.w);
        *(uint4*)&hbInit[i] = p;
        return;
    }
    if (bid == 528) {                     // zero flags (1024 words)
#pragma unroll
        for (int j = 0; j < 4; ++j)
            flags[tid + 256 * j] = 0u;
        return;
    }
    if (bid >= 785) {                     // Wout conversion
        size_t i = ((size_t)(bid - 785) * 256 + tid) * 8;
        float4 a = *(const float4*)&Wout[i];
        float4 c = *(const float4*)&Wout[i + 4];
        uint4 p;
        p.x = pack2(a.x, a.y); p.y = pack2(a.z, a.w);
        p.z = pack2(c.x, c.y); p.w = pack2(c.z, c.w);
        *(uint4*)&WbOut[i] = p;
        return;
    }

    // ---------------- kxwm GEMM: blocks 529..784 ----------------
    int u = bid - 529;
    int m0 = (u & 31) * 128, n0 = (u >> 5) * 128;
    if (tid < 128) {
        int row = m0 + tid;
        int t = row & (T_SEQ - 1);
        toks[tid] = (t == 0) ? SOS_TOK : target[row];
    }
    __syncthreads();

    v4f acc[4][4] = {};
    int lane = tid & 63, wv = tid >> 6, wm = wv >> 1, wn = wv & 1;
    int ar = lane & 15, ko = (lane >> 4) * 8;

    for (int k0 = 0; k0 < E_DIM; k0 += 32) {
#pragma unroll
        for (int l = 0; l < 2; ++l) {
            int c = tid + l * 256;
            int r = c >> 2, ko8 = (c & 3) * 8;
            const float* asrc = &emb[(size_t)toks[r] * E_DIM + k0 + ko8];
            float4 x = *(const float4*)asrc;
            float4 y = *(const float4*)(asrc + 4);
            uint4 p;
            p.x = pack2(x.x, x.y); p.y = pack2(x.z, x.w);
            p.z = pack2(y.x, y.y); p.w = pack2(y.z, y.w);
            *(uint4*)&As[r * 32 + ko8] = p;
            const float* bsrc = &Wih[(size_t)(n0 + r) * E_DIM + k0 + ko8];
            float4 uu = *(const float4*)bsrc;
            float4 vv = *(const float4*)(bsrc + 4);
            uint4 q;
            q.x = pack2(uu.x, uu.y); q.y = pack2(uu.z, uu.w);
            q.z = pack2(vv.x, vv.y); q.w = pack2(vv.z, vv.w);
            *(uint4*)&Bs[r * 32 + ko8] = q;
        }
        __syncthreads();

        short8 a[4], bfr[4];
#pragma unroll
        for (int i = 0; i < 4; ++i)
            a[i] = *(const short8*)&As[(wm * 64 + i * 16 + ar) * 32 + ko];
#pragma unroll
        for (int jj = 0; jj < 4; ++jj)
            bfr[jj] = *(const short8*)&Bs[(wn * 64 + jj * 16 + ar) * 32 + ko];
#pragma unroll
        for (int i = 0; i < 4; ++i)
#pragma unroll
            for (int jj = 0; jj < 4; ++jj)
                acc[i][jj] = __builtin_amdgcn_mfma_f32_16x16x32_bf16(
                    a[i], bfr[jj], acc[i][jj], 0, 0, 0);
        __syncthreads();
    }

    int fr = lane & 15, fq = lane >> 4;
#pragma unroll
    for (int jj = 0; jj < 4; ++jj) {
        int col = n0 + wn * 64 + jj * 16 + fr;
        float bias = bih[col] + bhh[col];
#pragma unroll
        for (int i = 0; i < 4; ++i) {
            int row = m0 + wm * 64 + i * 16 + fq * 4;
#pragma unroll
            for (int q = 0; q < 4; ++q) {
                int m = row + q;                 // = b*T + t
                int b = m >> 7, t = m & (T_SEQ - 1);
                xW[((size_t)t * B_SZ + b) * H_DIM + col] = acc[i][jj][q] + bias;
            }
        }
    }
}

// ---------------------------------------------------------------------------
// kfused: (32 + NCONS) blocks x 256 thr — VERBATIM R20/R21 except NCONS=128.
//  blocks 0..31       : producers (R15/R17 body).
//  blocks 32..32+NCONS: consumers. BBF=true: M-PAIRED schedule. BBF=false:
//                       single-tile fallback (fp32 B reg-packed).
// ---------------------------------------------------------------------------
template <bool BBF>
__global__ __launch_bounds__(256) void kfused(const uint16_t* __restrict__ hbInit,
                                              const uint16_t* __restrict__ WbHH,
                                              const float* __restrict__ xW,
                                              uint16_t* __restrict__ Hb,
                                              uint32_t* __restrict__ flags,
                                              const void* __restrict__ Bop,
                                              const float* __restrict__ bout,
                                              float* __restrict__ out) {
    __shared__ __align__(16) uint16_t As0[128 * 32];
    __shared__ __align__(16) uint16_t As1[128 * 32];
    __shared__ __align__(16) uint16_t Bs[128 * 32];
    int tid = threadIdx.x;
    int lane = tid & 63;

    if (blockIdx.x < 32) {
        // ---------------- producer: recurrence (R15/R17 body, verbatim) ---
        __builtin_amdgcn_s_setprio(1);
        int blk = blockIdx.x;
        int bg = blk & 1, ngg = blk >> 1;
        int w = tid >> 6;
        int ncol0 = ngg * 64 + w * 16;
        int lr = lane & 15, lk = (lane >> 4) * 8;

        short8 wf[32];
        const uint16_t* wrow = WbHH + (size_t)(ncol0 + lr) * H_DIM + lk;
#pragma unroll
        for (int kt = 0; kt < 32; ++kt)
            wf[kt] = *(const short8*)(wrow + (size_t)kt * 32);

        int brow = bg * 16 + lr;
        int eb = bg * 16 + (lane >> 4) * 4;
        int en = ncol0 + lr;
        uint32_t* Hb32 = (uint32_t*)Hb;
        uint32_t* myflag = flags + (size_t)(bg * 16 + ngg) * 32;
        const uint32_t* grpflags = flags + (size_t)(bg * 16) * 32;

        for (int t = 0; t < T_SEQ; ++t) {
            const uint16_t* arow =
                ((t == 0) ? hbInit : Hb + (size_t)(t - 1) * B_SZ * H_DIM)
                + (size_t)brow * H_DIM + lk;

            float xv[4];
#pragma unroll
            for (int q = 0; q < 4; ++q)
                xv[q] = xW[((size_t)t * B_SZ + eb + q) * H_DIM + en];

            v4f ac0 = {0.f,0.f,0.f,0.f}, ac1 = {0.f,0.f,0.f,0.f};
            v4f ac2 = {0.f,0.f,0.f,0.f}, ac3 = {0.f,0.f,0.f,0.f};
            short8 af0[16], af1[16];
#pragma unroll
            for (int kt = 0; kt < 16; ++kt)
                af0[kt] = *(const short8*)(arow + (size_t)kt * 32);
#pragma unroll
            for (int kt = 0; kt < 16; ++kt)
                af1[kt] = *(const short8*)(arow + 512 + (size_t)kt * 32);
#pragma unroll
            for (int kt = 0; kt < 16; ++kt) {
                v4f* a = (kt & 3) == 0 ? &ac0 : (kt & 3) == 1 ? &ac1
                        : (kt & 3) == 2 ? &ac2 : &ac3;
                *a = __builtin_amdgcn_mfma_f32_16x16x32_bf16(af0[kt], wf[kt], *a, 0, 0, 0);
            }
#pragma unroll
            for (int kt = 0; kt < 16; ++kt) {
                v4f* a = (kt & 3) == 0 ? &ac0 : (kt & 3) == 1 ? &ac1
                        : (kt & 3) == 2 ? &ac2 : &ac3;
                *a = __builtin_amdgcn_mfma_f32_16x16x32_bf16(af1[kt], wf[16 + kt], *a, 0, 0, 0);
            }
            v4f acc = (ac0 + ac1) + (ac2 + ac3);

            float hv[4];
#pragma unroll
            for (int q = 0; q < 4; ++q)
                hv[q] = tanhf(acc[q] + xv[q]);

#pragma unroll
            for (int q = 0; q < 4; ++q) {
                float pv = __shfl_xor(hv[q], 1);
                bool mine = ((lane & 1) == 0) ? (q < 2) : (q >= 2);
                if (mine) {
                    uint32_t word = (lane & 1) ? pack2(pv, hv[q]) : pack2(hv[q], pv);
                    size_t i32 = (((size_t)t * B_SZ + eb + q) * H_DIM
                                  + (size_t)(en & ~1)) >> 1;
                    __hip_atomic_store(&Hb32[i32], word, __ATOMIC_RELAXED,
                                       __HIP_MEMORY_SCOPE_AGENT);
                }
            }

            __syncthreads();   // drain all waves' stores before arrival
            if (tid == 0)
                __hip_atomic_store(myflag, (uint32_t)(t + 1), __ATOMIC_RELEASE,
                                   __HIP_MEMORY_SCOPE_AGENT);
            if (t < T_SEQ - 1) {
                if (tid < 16) {
                    const uint32_t* f = grpflags + (size_t)tid * 32;
                    while (__hip_atomic_load(f, __ATOMIC_RELAXED,
                                             __HIP_MEMORY_SCOPE_AGENT) <= (uint32_t)t)
                        __builtin_amdgcn_s_sleep(2);
                }
                if (tid == 0)
                    (void)__hip_atomic_load(myflag, __ATOMIC_ACQUIRE,
                                            __HIP_MEMORY_SCOPE_AGENT);
                __syncthreads();
            }
        }
    } else {
        // ---------------- consumer: decode GEMM -----------------
        int c = blockIdx.x - 32;
        int wv = tid >> 6, wm = wv >> 1, wn = wv & 1;
        int ar = lane & 15, ko = (lane >> 4) * 8;
        int sx = BBF ? (((ar >> 1) & 3) << 3) : 0;
        int fr = lane & 15, fq = lane >> 4;
        int gate_seen = 0;
        const uint32_t* proxyf = flags + (size_t)(c & 31) * 32;

        const uint16_t* Bb = (const uint16_t*)Bop;
        const float*    Bf = (const float*)Bop;

        if constexpr (BBF) {
            // M-paired schedule: unit p -> mtp {2j,2j+1} x nt
            for (int p = c; p < NPAIR; p += NCONS) {
                int m2 = p / 250, nt = p - m2 * 250;
                int need = 8 * m2 + 8;
                if (need > gate_seen) {
                    if (tid == 0) {
                        while (__hip_atomic_load(proxyf, __ATOMIC_RELAXED,
                                                 __HIP_MEMORY_SCOPE_AGENT) < (uint32_t)need)
                            __builtin_amdgcn_s_sleep(32);
                    }
                    __syncthreads();
                    if (tid < 32) {
                        const uint32_t* f = flags + (size_t)tid * 32;
                        while (__hip_atomic_load(f, __ATOMIC_RELAXED,
                                                 __HIP_MEMORY_SCOPE_AGENT) < (uint32_t)need)
                            __builtin_amdgcn_s_sleep(2);
                    }
                    __syncthreads();
                    if (tid == 0)
                        (void)__hip_atomic_load(flags, __ATOMIC_ACQUIRE,
                                                __HIP_MEMORY_SCOPE_AGENT);
                    __syncthreads();
                    gate_seen = need;
                }

                int m0 = m2 * 256, n0 = nt * 128;
                v4f acc[2][4][4] = {};

                for (int k0 = 0; k0 < H_DIM; k0 += 32) {
                    int wb = tid & ~63;
#pragma unroll
                    for (int l = 0; l < 2; ++l) {
                        int cc = tid + l * 256;
                        int r = cc >> 2;
                        int gsw = ((cc & 3) ^ ((cc >> 3) & 3)) * 8;
                        gload16(&Hb[(size_t)(m0 + r) * H_DIM + k0 + gsw],
                                (char*)As0 + (size_t)(wb + l * 256) * 16);
                        gload16(&Hb[(size_t)(m0 + 128 + r) * H_DIM + k0 + gsw],
                                (char*)As1 + (size_t)(wb + l * 256) * 16);
                        gload16(&Bb[(size_t)(n0 + r) * H_DIM + k0 + gsw],
                                (char*)Bs + (size_t)(wb + l * 256) * 16);
                    }
                    __syncthreads();

                    short8 a0[4], a1[4], bfr[4];
#pragma unroll
                    for (int i = 0; i < 4; ++i) {
                        a0[i] = *(const short8*)&As0[(wm * 64 + i * 16 + ar) * 32 + (ko ^ sx)];
                        a1[i] = *(const short8*)&As1[(wm * 64 + i * 16 + ar) * 32 + (ko ^ sx)];
                    }
#pragma unroll
                    for (int jj = 0; jj < 4; ++jj)
                        bfr[jj] = *(const short8*)&Bs[(wn * 64 + jj * 16 + ar) * 32 + (ko ^ sx)];
#pragma unroll
                    for (int i = 0; i < 4; ++i)
#pragma unroll
                        for (int jj = 0; jj < 4; ++jj) {
                            acc[0][i][jj] = __builtin_amdgcn_mfma_f32_16x16x32_bf16(
                                a0[i], bfr[jj], acc[0][i][jj], 0, 0, 0);
                            acc[1][i][jj] = __builtin_amdgcn_mfma_f32_16x16x32_bf16(
                                a1[i], bfr[jj], acc[1][i][jj], 0, 0, 0);
                        }
                    __syncthreads();
                }

#pragma unroll
                for (int h = 0; h < 2; ++h) {
#pragma unroll
                    for (int jj = 0; jj < 4; ++jj) {
                        int col = n0 + wn * 64 + jj * 16 + fr;
                        float bo = bout[col];
#pragma unroll
                        for (int i = 0; i < 4; ++i) {
                            int rbase = wm * 64 + i * 16 + fq * 4;
#pragma unroll
                            for (int q = 0; q < 4; ++q) {
                                int mp = m0 + h * 128 + rbase + q;  // [t][b] row
                                int tt = mp >> 5, bb = mp & 31;
                                out[((size_t)bb * T_SEQ + tt) * V_DIM + col] =
                                    acc[h][i][jj][q] + bo;
                            }
                        }
                    }
                }
            }
        } else {
            // single-tile fallback (fp32 B reg-packed)
            for (int g = c; g < NTILES; g += NCONS) {
                int mtp = g / 250, nt = g - mtp * 250;
                int need = 4 * mtp + 4;
                if (need > gate_seen) {
                    if (tid == 0) {
                        while (__hip_atomic_load(proxyf, __ATOMIC_RELAXED,
                                                 __HIP_MEMORY_SCOPE_AGENT) < (uint32_t)need)
                            __builtin_amdgcn_s_sleep(32);
                    }
                    __syncthreads();
                    if (tid < 32) {
                        const uint32_t* f = flags + (size_t)tid * 32;
                        while (__hip_atomic_load(f, __ATOMIC_RELAXED,
                                                 __HIP_MEMORY_SCOPE_AGENT) < (uint32_t)need)
                            __builtin_amdgcn_s_sleep(2);
                    }
                    __syncthreads();
                    if (tid == 0)
                        (void)__hip_atomic_load(flags, __ATOMIC_ACQUIRE,
                                                __HIP_MEMORY_SCOPE_AGENT);
                    __syncthreads();
                    gate_seen = need;
                }

                int m0 = mtp * 128, n0 = nt * 128;
                v4f acc[4][4] = {};

                for (int k0 = 0; k0 < H_DIM; k0 += 32) {
                    int wb = tid & ~63;
#pragma unroll
                    for (int l = 0; l < 2; ++l) {
                        int cc = tid + l * 256;
                        int r = cc >> 2, ko8 = (cc & 3) * 8;
                        gload16(&Hb[(size_t)(m0 + r) * H_DIM + k0 + ko8],
                                (char*)As0 + (size_t)(wb + l * 256) * 16);
                        const float* src = &Bf[(size_t)(n0 + r) * H_DIM + k0 + ko8];
                        float4 x = *(const float4*)src;
                        float4 y = *(const float4*)(src + 4);
                        uint4 p;
                        p.x = pack2(x.x, x.y); p.y = pack2(x.z, x.w);
                        p.z = pack2(y.x, y.y); p.w = pack2(y.z, y.w);
                        *(uint4*)&Bs[r * 32 + ko8] = p;
                    }
                    __syncthreads();

                    short8 a[4], bfr[4];
#pragma unroll
                    for (int i = 0; i < 4; ++i)
                        a[i] = *(const short8*)&As0[(wm * 64 + i * 16 + ar) * 32 + ko];
#pragma unroll
                    for (int jj = 0; jj < 4; ++jj)
                        bfr[jj] = *(const short8*)&Bs[(wn * 64 + jj * 16 + ar) * 32 + ko];
#pragma unroll
                    for (int i = 0; i < 4; ++i)
#pragma unroll
                        for (int jj = 0; jj < 4; ++jj)
                            acc[i][jj] = __builtin_amdgcn_mfma_f32_16x16x32_bf16(
                                a[i], bfr[jj], acc[i][jj], 0, 0, 0);
                    __syncthreads();
                }

#pragma unroll
                for (int jj = 0; jj < 4; ++jj) {
                    int col = n0 + wn * 64 + jj * 16 + fr;
                    float bo = bout[col];
#pragma unroll
                    for (int i = 0; i < 4; ++i) {
                        int rbase = wm * 64 + i * 16 + fq * 4;
#pragma unroll
                        for (int q = 0; q < 4; ++q) {
                            int mp = m0 + rbase + q;
                            int tt = mp >> 5, bb = mp & 31;
                            out[((size_t)bb * T_SEQ + tt) * V_DIM + col] =
                                acc[i][jj][q] + bo;
                        }
                    }
                }
            }
        }
    }
}

// ---------------------------------------------------------------------------
extern "C" void kernel_launch(void* const* d_in, const int* in_sizes, int n_in,
                              void* d_out, int out_size, void* d_ws, size_t ws_size,
                              hipStream_t stream) {
    const int*   target = (const int*)d_in[0];
    const float* h0     = (const float*)d_in[1];
    const float* emb    = (const float*)d_in[2];
    const float* Wih    = (const float*)d_in[3];
    const float* bih    = (const float*)d_in[4];
    const float* Whh    = (const float*)d_in[5];
    const float* bhh    = (const float*)d_in[6];
    const float* Wout   = (const float*)d_in[7];
    const float* bout   = (const float*)d_in[8];
    float* out = (float*)d_out;

    char* ws = (char*)d_ws;
    // ws layout (bytes):
    float*    xW     = (float*)(ws);                    // 16,777,216
    uint16_t* WbHH   = (uint16_t*)(ws + 16777216);      //  2,097,152
    uint16_t* hbInit = (uint16_t*)(ws + 18874368);      //     65,536
    uint32_t* flags  = (uint32_t*)(ws + 18939904);      //      4,096
    uint16_t* Hb     = (uint16_t*)(ws + 18944000);      //  8,388,608 -> 27,332,608
    uint16_t* WbOut  = (uint16_t*)(ws + 27332608);      // 65,536,000 -> 92,868,608
    const bool wbok = ws_size >= 92868608ull;           // R1 evidence: ws >= 95.2MB

    int nprep = wbok ? (785 + 16000) : 785;
    kprep<<<nprep, 256, 0, stream>>>(Whh, WbHH, h0, hbInit, flags,
                                     target, emb, Wih, bih, bhh, xW,
                                     Wout, WbOut);

    if (wbok) {
        kfused<true><<<32 + NCONS, 256, 0, stream>>>(hbInit, WbHH, xW, Hb, flags,
                                                     (const void*)WbOut, bout, out);
    } else {
        kfused<false><<<32 + NCONS, 256, 0, stream>>>(hbInit, WbHH, xW, Hb, flags,
                                                      (const void*)Wout, bout, out);
    }
}

// Round 23
// 1030.980 us; speedup vs baseline: 1.1626x; 1.1626x over previous
//
#include <hip/hip_runtime.h>
#include <stdint.h>

#define T_SEQ 128
#define B_SZ  32
#define H_DIM 1024
#define E_DIM 512
#define V_DIM 32000
#define SOS_TOK 1
#define NCONS 224     // consumers; grid 32+224 = 256 = #CUs -> 1 block/CU
#define NTILES 8000   // 32 mtp x 250 nt (BBF=false path)
#define NPAIR 4000    // 16 m2 x 250 nt  (BBF=true paired path)

typedef float v4f __attribute__((ext_vector_type(4)));
typedef short short8 __attribute__((ext_vector_type(8)));

// RNE float->bf16
__device__ inline uint16_t f2bf(float x) {
    uint32_t u = __float_as_uint(x);
    uint32_t r = (u + 0x7fffu + ((u >> 16) & 1u)) >> 16;
    return (uint16_t)r;
}
__device__ inline uint32_t pack2(float a, float b) {
    return (uint32_t)f2bf(a) | ((uint32_t)f2bf(b) << 16);
}

// async global->LDS, 16B per lane. lds base must be wave-uniform.
__device__ inline void gload16(const void* g, void* l) {
    __builtin_amdgcn_global_load_lds(
        (const __attribute__((address_space(1))) uint32_t*)g,
        (__attribute__((address_space(3))) uint32_t*)l, 16, 0, 0);
}

// ---------------------------------------------------------------------------
// kprep: single prologue launch.
//   blocks [0,512)        : Whh fp32->bf16 (2048 elts/block)
//   blocks [512,528)      : h0 fp32->bf16
//   block  528            : zero flags (4096 B)
//   blocks [529,785)      : kxwm GEMM (xW = emb[tok].Wih^T + biases), 128x128
//   blocks [785,785+16000): Wout fp32->bf16 (only launched when wbok)
// ---------------------------------------------------------------------------
__global__ __launch_bounds__(256) void kprep(const float* __restrict__ Whh,
                                             uint16_t* __restrict__ WbHH,
                                             const float* __restrict__ h0,
                                             uint16_t* __restrict__ hbInit,
                                             uint32_t* __restrict__ flags,
                                             const int* __restrict__ target,
                                             const float* __restrict__ emb,
                                             const float* __restrict__ Wih,
                                             const float* __restrict__ bih,
                                             const float* __restrict__ bhh,
                                             float* __restrict__ xW,
                                             const float* __restrict__ Wout,
                                             uint16_t* __restrict__ WbOut) {
    __shared__ __align__(16) uint16_t As[128 * 32];
    __shared__ __align__(16) uint16_t Bs[128 * 32];
    __shared__ int toks[128];
    int bid = blockIdx.x;
    int tid = threadIdx.x;

    if (bid < 512) {                      // Whh conversion
        size_t i = ((size_t)bid * 256 + tid) * 8;
        float4 a = *(const float4*)&Whh[i];
        float4 c = *(const float4*)&Whh[i + 4];
        uint4 p;
        p.x = pack2(a.x, a.y); p.y = pack2(a.z, a.w);
        p.z = pack2(c.x, c.y); p.w = pack2(c.z, c.w);
        *(uint4*)&WbHH[i] = p;
        return;
    }
    if (bid < 528) {                      // h0 conversion
        size_t i = ((size_t)(bid - 512) * 256 + tid) * 8;
        float4 a = *(const float4*)&h0[i];
        float4 c = *(const float4*)&h0[i + 4];
        uint4 p;
        p.x = pack2(a.x, a.y); p.y = pack2(a.z, a.w);
        p.z = pack2(c.x, c.y); p.w = pack2(c.z, c.w);
        *(uint4*)&hbInit[i] = p;
        return;
    }
    if (bid == 528) {                     // zero flags (1024 words)
#pragma unroll
        for (int j = 0; j < 4; ++j)
            flags[tid + 256 * j] = 0u;
        return;
    }
    if (bid >= 785) {                     // Wout conversion
        size_t i = ((size_t)(bid - 785) * 256 + tid) * 8;
        float4 a = *(const float4*)&Wout[i];
        float4 c = *(const float4*)&Wout[i + 4];
        uint4 p;
        p.x = pack2(a.x, a.y); p.y = pack2(a.z, a.w);
        p.z = pack2(c.x, c.y); p.w = pack2(c.z, c.w);
        *(uint4*)&WbOut[i] = p;
        return;
    }

    // ---------------- kxwm GEMM: blocks 529..784 ----------------
    int u = bid - 529;
    int m0 = (u & 31) * 128, n0 = (u >> 5) * 128;
    if (tid < 128) {
        int row = m0 + tid;
        int t = row & (T_SEQ - 1);
        toks[tid] = (t == 0) ? SOS_TOK : target[row];
    }
    __syncthreads();

    v4f acc[4][4] = {};
    int lane = tid & 63, wv = tid >> 6, wm = wv >> 1, wn = wv & 1;
    int ar = lane & 15, ko = (lane >> 4) * 8;

    for (int k0 = 0; k0 < E_DIM; k0 += 32) {
#pragma unroll
        for (int l = 0; l < 2; ++l) {
            int c = tid + l * 256;
            int r = c >> 2, ko8 = (c & 3) * 8;
            const float* asrc = &emb[(size_t)toks[r] * E_DIM + k0 + ko8];
            float4 x = *(const float4*)asrc;
            float4 y = *(const float4*)(asrc + 4);
            uint4 p;
            p.x = pack2(x.x, x.y); p.y = pack2(x.z, x.w);
            p.z = pack2(y.x, y.y); p.w = pack2(y.z, y.w);
            *(uint4*)&As[r * 32 + ko8] = p;
            const float* bsrc = &Wih[(size_t)(n0 + r) * E_DIM + k0 + ko8];
            float4 uu = *(const float4*)bsrc;
            float4 vv = *(const float4*)(bsrc + 4);
            uint4 q;
            q.x = pack2(uu.x, uu.y); q.y = pack2(uu.z, uu.w);
            q.z = pack2(vv.x, vv.y); q.w = pack2(vv.z, vv.w);
            *(uint4*)&Bs[r * 32 + ko8] = q;
        }
        __syncthreads();

        short8 a[4], bfr[4];
#pragma unroll
        for (int i = 0; i < 4; ++i)
            a[i] = *(const short8*)&As[(wm * 64 + i * 16 + ar) * 32 + ko];
#pragma unroll
        for (int jj = 0; jj < 4; ++jj)
            bfr[jj] = *(const short8*)&Bs[(wn * 64 + jj * 16 + ar) * 32 + ko];
#pragma unroll
        for (int i = 0; i < 4; ++i)
#pragma unroll
            for (int jj = 0; jj < 4; ++jj)
                acc[i][jj] = __builtin_amdgcn_mfma_f32_16x16x32_bf16(
                    a[i], bfr[jj], acc[i][jj], 0, 0, 0);
        __syncthreads();
    }

    int fr = lane & 15, fq = lane >> 4;
#pragma unroll
    for (int jj = 0; jj < 4; ++jj) {
        int col = n0 + wn * 64 + jj * 16 + fr;
        float bias = bih[col] + bhh[col];
#pragma unroll
        for (int i = 0; i < 4; ++i) {
            int row = m0 + wm * 64 + i * 16 + fq * 4;
#pragma unroll
            for (int q = 0; q < 4; ++q) {
                int m = row + q;                 // = b*T + t
                int b = m >> 7, t = m & (T_SEQ - 1);
                xW[((size_t)t * B_SZ + b) * H_DIM + col] = acc[i][jj][q] + bias;
            }
        }
    }
}

// ---------------------------------------------------------------------------
// kfused: 256 blocks x 256 thr (1 block/CU) — best configuration (R21).
//  blocks 0..31  : producers (R15/R17 body).
//  blocks 32..255: consumers. BBF=true: M-PAIRED schedule (mtp {2j,2j+1} x
//                  one nt per B stage; halves W_out re-reads and gates).
//                  BBF=false: single-tile fallback (fp32 B reg-packed).
// ---------------------------------------------------------------------------
template <bool BBF>
__global__ __launch_bounds__(256) void kfused(const uint16_t* __restrict__ hbInit,
                                              const uint16_t* __restrict__ WbHH,
                                              const float* __restrict__ xW,
                                              uint16_t* __restrict__ Hb,
                                              uint32_t* __restrict__ flags,
                                              const void* __restrict__ Bop,
                                              const float* __restrict__ bout,
                                              float* __restrict__ out) {
    __shared__ __align__(16) uint16_t As0[128 * 32];
    __shared__ __align__(16) uint16_t As1[128 * 32];
    __shared__ __align__(16) uint16_t Bs[128 * 32];
    int tid = threadIdx.x;
    int lane = tid & 63;

    if (blockIdx.x < 32) {
        // ---------------- producer: recurrence (R15/R17 body, verbatim) ---
        __builtin_amdgcn_s_setprio(1);
        int blk = blockIdx.x;
        int bg = blk & 1, ngg = blk >> 1;
        int w = tid >> 6;
        int ncol0 = ngg * 64 + w * 16;
        int lr = lane & 15, lk = (lane >> 4) * 8;

        short8 wf[32];
        const uint16_t* wrow = WbHH + (size_t)(ncol0 + lr) * H_DIM + lk;
#pragma unroll
        for (int kt = 0; kt < 32; ++kt)
            wf[kt] = *(const short8*)(wrow + (size_t)kt * 32);

        int brow = bg * 16 + lr;
        int eb = bg * 16 + (lane >> 4) * 4;
        int en = ncol0 + lr;
        uint32_t* Hb32 = (uint32_t*)Hb;
        uint32_t* myflag = flags + (size_t)(bg * 16 + ngg) * 32;
        const uint32_t* grpflags = flags + (size_t)(bg * 16) * 32;

        for (int t = 0; t < T_SEQ; ++t) {
            const uint16_t* arow =
                ((t == 0) ? hbInit : Hb + (size_t)(t - 1) * B_SZ * H_DIM)
                + (size_t)brow * H_DIM + lk;

            float xv[4];
#pragma unroll
            for (int q = 0; q < 4; ++q)
                xv[q] = xW[((size_t)t * B_SZ + eb + q) * H_DIM + en];

            v4f ac0 = {0.f,0.f,0.f,0.f}, ac1 = {0.f,0.f,0.f,0.f};
            v4f ac2 = {0.f,0.f,0.f,0.f}, ac3 = {0.f,0.f,0.f,0.f};
            short8 af0[16], af1[16];
#pragma unroll
            for (int kt = 0; kt < 16; ++kt)
                af0[kt] = *(const short8*)(arow + (size_t)kt * 32);
#pragma unroll
            for (int kt = 0; kt < 16; ++kt)
                af1[kt] = *(const short8*)(arow + 512 + (size_t)kt * 32);
#pragma unroll
            for (int kt = 0; kt < 16; ++kt) {
                v4f* a = (kt & 3) == 0 ? &ac0 : (kt & 3) == 1 ? &ac1
                        : (kt & 3) == 2 ? &ac2 : &ac3;
                *a = __builtin_amdgcn_mfma_f32_16x16x32_bf16(af0[kt], wf[kt], *a, 0, 0, 0);
            }
#pragma unroll
            for (int kt = 0; kt < 16; ++kt) {
                v4f* a = (kt & 3) == 0 ? &ac0 : (kt & 3) == 1 ? &ac1
                        : (kt & 3) == 2 ? &ac2 : &ac3;
                *a = __builtin_amdgcn_mfma_f32_16x16x32_bf16(af1[kt], wf[16 + kt], *a, 0, 0, 0);
            }
            v4f acc = (ac0 + ac1) + (ac2 + ac3);

            float hv[4];
#pragma unroll
            for (int q = 0; q < 4; ++q)
                hv[q] = tanhf(acc[q] + xv[q]);

#pragma unroll
            for (int q = 0; q < 4; ++q) {
                float pv = __shfl_xor(hv[q], 1);
                bool mine = ((lane & 1) == 0) ? (q < 2) : (q >= 2);
                if (mine) {
                    uint32_t word = (lane & 1) ? pack2(pv, hv[q]) : pack2(hv[q], pv);
                    size_t i32 = (((size_t)t * B_SZ + eb + q) * H_DIM
                                  + (size_t)(en & ~1)) >> 1;
                    __hip_atomic_store(&Hb32[i32], word, __ATOMIC_RELAXED,
                                       __HIP_MEMORY_SCOPE_AGENT);
                }
            }

            __syncthreads();   // drain all waves' stores before arrival
            if (tid == 0)
                __hip_atomic_store(myflag, (uint32_t)(t + 1), __ATOMIC_RELEASE,
                                   __HIP_MEMORY_SCOPE_AGENT);
            if (t < T_SEQ - 1) {
                if (tid < 16) {
                    const uint32_t* f = grpflags + (size_t)tid * 32;
                    while (__hip_atomic_load(f, __ATOMIC_RELAXED,
                                             __HIP_MEMORY_SCOPE_AGENT) <= (uint32_t)t)
                        __builtin_amdgcn_s_sleep(2);
                }
                if (tid == 0)
                    (void)__hip_atomic_load(myflag, __ATOMIC_ACQUIRE,
                                            __HIP_MEMORY_SCOPE_AGENT);
                __syncthreads();
            }
        }
    } else {
        // ---------------- consumer: decode GEMM -----------------
        int c = blockIdx.x - 32;
        int wv = tid >> 6, wm = wv >> 1, wn = wv & 1;
        int ar = lane & 15, ko = (lane >> 4) * 8;
        int sx = BBF ? (((ar >> 1) & 3) << 3) : 0;
        int fr = lane & 15, fq = lane >> 4;
        int gate_seen = 0;
        const uint32_t* proxyf = flags + (size_t)(c & 31) * 32;

        const uint16_t* Bb = (const uint16_t*)Bop;
        const float*    Bf = (const float*)Bop;

        if constexpr (BBF) {
            // M-paired schedule: unit p -> mtp {2j,2j+1} x nt
            for (int p = c; p < NPAIR; p += NCONS) {
                int m2 = p / 250, nt = p - m2 * 250;
                int need = 8 * m2 + 8;
                if (need > gate_seen) {
                    if (tid == 0) {
                        while (__hip_atomic_load(proxyf, __ATOMIC_RELAXED,
                                                 __HIP_MEMORY_SCOPE_AGENT) < (uint32_t)need)
                            __builtin_amdgcn_s_sleep(32);
                    }
                    __syncthreads();
                    if (tid < 32) {
                        const uint32_t* f = flags + (size_t)tid * 32;
                        while (__hip_atomic_load(f, __ATOMIC_RELAXED,
                                                 __HIP_MEMORY_SCOPE_AGENT) < (uint32_t)need)
                            __builtin_amdgcn_s_sleep(2);
                    }
                    __syncthreads();
                    if (tid == 0)
                        (void)__hip_atomic_load(flags, __ATOMIC_ACQUIRE,
                                                __HIP_MEMORY_SCOPE_AGENT);
                    __syncthreads();
                    gate_seen = need;
                }

                int m0 = m2 * 256, n0 = nt * 128;
                v4f acc[2][4][4] = {};

                for (int k0 = 0; k0 < H_DIM; k0 += 32) {
                    int wb = tid & ~63;
#pragma unroll
                    for (int l = 0; l < 2; ++l) {
                        int cc = tid + l * 256;
                        int r = cc >> 2;
                        int gsw = ((cc & 3) ^ ((cc >> 3) & 3)) * 8;
                        gload16(&Hb[(size_t)(m0 + r) * H_DIM + k0 + gsw],
                                (char*)As0 + (size_t)(wb + l * 256) * 16);
                        gload16(&Hb[(size_t)(m0 + 128 + r) * H_DIM + k0 + gsw],
                                (char*)As1 + (size_t)(wb + l * 256) * 16);
                        gload16(&Bb[(size_t)(n0 + r) * H_DIM + k0 + gsw],
                                (char*)Bs + (size_t)(wb + l * 256) * 16);
                    }
                    __syncthreads();

                    short8 a0[4], a1[4], bfr[4];
#pragma unroll
                    for (int i = 0; i < 4; ++i) {
                        a0[i] = *(const short8*)&As0[(wm * 64 + i * 16 + ar) * 32 + (ko ^ sx)];
                        a1[i] = *(const short8*)&As1[(wm * 64 + i * 16 + ar) * 32 + (ko ^ sx)];
                    }
#pragma unroll
                    for (int jj = 0; jj < 4; ++jj)
                        bfr[jj] = *(const short8*)&Bs[(wn * 64 + jj * 16 + ar) * 32 + (ko ^ sx)];
#pragma unroll
                    for (int i = 0; i < 4; ++i)
#pragma unroll
                        for (int jj = 0; jj < 4; ++jj) {
                            acc[0][i][jj] = __builtin_amdgcn_mfma_f32_16x16x32_bf16(
                                a0[i], bfr[jj], acc[0][i][jj], 0, 0, 0);
                            acc[1][i][jj] = __builtin_amdgcn_mfma_f32_16x16x32_bf16(
                                a1[i], bfr[jj], acc[1][i][jj], 0, 0, 0);
                        }
                    __syncthreads();
                }

#pragma unroll
                for (int h = 0; h < 2; ++h) {
#pragma unroll
                    for (int jj = 0; jj < 4; ++jj) {
                        int col = n0 + wn * 64 + jj * 16 + fr;
                        float bo = bout[col];
#pragma unroll
                        for (int i = 0; i < 4; ++i) {
                            int rbase = wm * 64 + i * 16 + fq * 4;
#pragma unroll
                            for (int q = 0; q < 4; ++q) {
                                int mp = m0 + h * 128 + rbase + q;  // [t][b] row
                                int tt = mp >> 5, bb = mp & 31;
                                out[((size_t)bb * T_SEQ + tt) * V_DIM + col] =
                                    acc[h][i][jj][q] + bo;
                            }
                        }
                    }
                }
            }
        } else {
            // single-tile fallback (fp32 B reg-packed)
            for (int g = c; g < NTILES; g += NCONS) {
                int mtp = g / 250, nt = g - mtp * 250;
                int need = 4 * mtp + 4;
                if (need > gate_seen) {
                    if (tid == 0) {
                        while (__hip_atomic_load(proxyf, __ATOMIC_RELAXED,
                                                 __HIP_MEMORY_SCOPE_AGENT) < (uint32_t)need)
                            __builtin_amdgcn_s_sleep(32);
                    }
                    __syncthreads();
                    if (tid < 32) {
                        const uint32_t* f = flags + (size_t)tid * 32;
                        while (__hip_atomic_load(f, __ATOMIC_RELAXED,
                                                 __HIP_MEMORY_SCOPE_AGENT) < (uint32_t)need)
                            __builtin_amdgcn_s_sleep(2);
                    }
                    __syncthreads();
                    if (tid == 0)
                        (void)__hip_atomic_load(flags, __ATOMIC_ACQUIRE,
                                                __HIP_MEMORY_SCOPE_AGENT);
                    __syncthreads();
                    gate_seen = need;
                }

                int m0 = mtp * 128, n0 = nt * 128;
                v4f acc[4][4] = {};

                for (int k0 = 0; k0 < H_DIM; k0 += 32) {
                    int wb = tid & ~63;
#pragma unroll
                    for (int l = 0; l < 2; ++l) {
                        int cc = tid + l * 256;
                        int r = cc >> 2, ko8 = (cc & 3) * 8;
                        gload16(&Hb[(size_t)(m0 + r) * H_DIM + k0 + ko8],
                                (char*)As0 + (size_t)(wb + l * 256) * 16);
                        const float* src = &Bf[(size_t)(n0 + r) * H_DIM + k0 + ko8];
                        float4 x = *(const float4*)src;
                        float4 y = *(const float4*)(src + 4);
                        uint4 p;
                        p.x = pack2(x.x, x.y); p.y = pack2(x.z, x.w);
                        p.z = pack2(y.x, y.y); p.w = pack2(y.z, y.w);
                        *(uint4*)&Bs[r * 32 + ko8] = p;
                    }
                    __syncthreads();

                    short8 a[4], bfr[4];
#pragma unroll
                    for (int i = 0; i < 4; ++i)
                        a[i] = *(const short8*)&As0[(wm * 64 + i * 16 + ar) * 32 + ko];
#pragma unroll
                    for (int jj = 0; jj < 4; ++jj)
                        bfr[jj] = *(const short8*)&Bs[(wn * 64 + jj * 16 + ar) * 32 + ko];
#pragma unroll
                    for (int i = 0; i < 4; ++i)
#pragma unroll
                        for (int jj = 0; jj < 4; ++jj)
                            acc[i][jj] = __builtin_amdgcn_mfma_f32_16x16x32_bf16(
                                a[i], bfr[jj], acc[i][jj], 0, 0, 0);
                    __syncthreads();
                }

#pragma unroll
                for (int jj = 0; jj < 4; ++jj) {
                    int col = n0 + wn * 64 + jj * 16 + fr;
                    float bo = bout[col];
#pragma unroll
                    for (int i = 0; i < 4; ++i) {
                        int rbase = wm * 64 + i * 16 + fq * 4;
#pragma unroll
                        for (int q = 0; q < 4; ++q) {
                            int mp = m0 + rbase + q;
                            int tt = mp >> 5, bb = mp & 31;
                            out[((size_t)bb * T_SEQ + tt) * V_DIM + col] =
                                acc[i][jj][q] + bo;
                        }
                    }
                }
            }
        }
    }
}

// ---------------------------------------------------------------------------
extern "C" void kernel_launch(void* const* d_in, const int* in_sizes, int n_in,
                              void* d_out, int out_size, void* d_ws, size_t ws_size,
                              hipStream_t stream) {
    const int*   target = (const int*)d_in[0];
    const float* h0     = (const float*)d_in[1];
    const float* emb    = (const float*)d_in[2];
    const float* Wih    = (const float*)d_in[3];
    const float* bih    = (const float*)d_in[4];
    const float* Whh    = (const float*)d_in[5];
    const float* bhh    = (const float*)d_in[6];
    const float* Wout   = (const float*)d_in[7];
    const float* bout   = (const float*)d_in[8];
    float* out = (float*)d_out;

    char* ws = (char*)d_ws;
    // ws layout (bytes):
    float*    xW     = (float*)(ws);                    // 16,777,216
    uint16_t* WbHH   = (uint16_t*)(ws + 16777216);      //  2,097,152
    uint16_t* hbInit = (uint16_t*)(ws + 18874368);      //     65,536
    uint32_t* flags  = (uint32_t*)(ws + 18939904);      //      4,096
    uint16_t* Hb     = (uint16_t*)(ws + 18944000);      //  8,388,608 -> 27,332,608
    uint16_t* WbOut  = (uint16_t*)(ws + 27332608);      // 65,536,000 -> 92,868,608
    const bool wbok = ws_size >= 92868608ull;           // R1 evidence: ws >= 95.2MB

    int nprep = wbok ? (785 + 16000) : 785;
    kprep<<<nprep, 256, 0, stream>>>(Whh, WbHH, h0, hbInit, flags,
                                     target, emb, Wih, bih, bhh, xW,
                                     Wout, WbOut);

    if (wbok) {
        kfused<true><<<32 + NCONS, 256, 0, stream>>>(hbInit, WbHH, xW, Hb, flags,
                                                     (const void*)WbOut, bout, out);
    } else {
        kfused<false><<<32 + NCONS, 256, 0, stream>>>(hbInit, WbHH, xW, Hb, flags,
                                                      (const void*)Wout, bout, out);
    }
}